// Round 7
// baseline (278.517 us; speedup 1.0000x reference)
//
#include <hip/hip_runtime.h>
#include <math.h>

typedef __attribute__((ext_vector_type(8))) __bf16 bf16x8;
typedef __attribute__((ext_vector_type(4))) __bf16 bf16x4;
typedef __attribute__((ext_vector_type(4))) float f32x4;

constexpr int kBATCH = 2;
constexpr int kS = 2048;
constexpr int kE = 1024;
constexpr int kH = 16;
constexpr int kD = 64;
constexpr float kScale = 0.125f;   // D^-0.5, pre-applied to Q in rope

// async global->LDS, 16B per lane. LDS dest is wave-uniform base + lane*16.
__device__ inline void gl2lds16(const void* g, void* l) {
    __builtin_amdgcn_global_load_lds((const __attribute__((address_space(1))) void*)g,
                                     (__attribute__((address_space(3))) void*)l, 16, 0, 0);
}

// ---------------------------------------------------------------------------
// fp32 -> bf16 convert, two buffers in one launch (range select).
// ---------------------------------------------------------------------------
__global__ __launch_bounds__(256) void cvt2_kernel(const float* __restrict__ a, __bf16* __restrict__ oa, int na,
                                                   const float* __restrict__ b, __bf16* __restrict__ ob) {
    int idx = (blockIdx.x * 256 + threadIdx.x) * 4;
    const float* src;
    __bf16* dst;
    if (idx < na) { src = a + idx; dst = oa + idx; }
    else          { src = b + (idx - na); dst = ob + (idx - na); }
    float4 f = *(const float4*)src;
    bf16x4 r;
    r[0] = (__bf16)f.x; r[1] = (__bf16)f.y; r[2] = (__bf16)f.z; r[3] = (__bf16)f.w;
    *(bf16x4*)dst = r;
}

// ---------------------------------------------------------------------------
// GEMM: C[m,n] = sum_k A[m,k] * W[n,k], bf16 in. Tile 128 x TN, BK=64,
// global_load_lds staging with XOR-chunk swizzle (conflict-free frag reads).
// ---------------------------------------------------------------------------
template <int TN, typename TC>
__global__ __launch_bounds__(256) void gemm_bt_kernel(const __bf16* __restrict__ A,
                                                      const __bf16* __restrict__ W,
                                                      TC* __restrict__ C,
                                                      int M, int N, int K) {
    constexpr int NI = TN / 32;        // n-frags per wave
    __shared__ __bf16 As[128 * 64] __attribute__((aligned(16)));
    __shared__ __bf16 Bs[TN * 64] __attribute__((aligned(16)));

    const int tid  = threadIdx.x;
    const int lane = tid & 63;
    const int quad = lane >> 4;
    const int l16  = lane & 15;
    const int rx   = l16 & 7;
    const int wave = tid >> 6;
    const int wm   = (wave >> 1) * 64;
    const int wn   = (wave & 1) * (TN / 2);
    const int m0   = blockIdx.y * 128;
    const int n0   = blockIdx.x * TN;

    const int srow8  = lane >> 3;                  // 0..7
    const int schunk = ((lane & 7) ^ srow8) * 8;   // swizzled source col (elems)

    f32x4 zero = {0.f, 0.f, 0.f, 0.f};
    f32x4 acc[4][NI];
#pragma unroll
    for (int i = 0; i < 4; ++i)
#pragma unroll
        for (int j = 0; j < NI; ++j) acc[i][j] = zero;

    for (int kt = 0; kt < K; kt += 64) {
        __syncthreads();   // previous tile's readers done
#pragma unroll
        for (int i = 0; i < 4; ++i) {
            int rbase = wave * 32 + i * 8;
            gl2lds16(A + (size_t)(m0 + rbase + srow8) * K + kt + schunk, &As[rbase * 64]);
        }
#pragma unroll
        for (int i = 0; i < NI; ++i) {
            int rbase = wave * (TN / 4) + i * 8;
            gl2lds16(W + (size_t)(n0 + rbase + srow8) * K + kt + schunk, &Bs[rbase * 64]);
        }
        __syncthreads();   // loads landed

#pragma unroll
        for (int kk = 0; kk < 2; ++kk) {
            bf16x8 af[4], bf[NI];
#pragma unroll
            for (int mi = 0; mi < 4; ++mi)
                af[mi] = *(const bf16x8*)(&As[(wm + mi * 16 + l16) * 64 + (((kk * 4 + quad) ^ rx)) * 8]);
#pragma unroll
            for (int ni = 0; ni < NI; ++ni)
                bf[ni] = *(const bf16x8*)(&Bs[(wn + ni * 16 + l16) * 64 + (((kk * 4 + quad) ^ rx)) * 8]);
#pragma unroll
            for (int mi = 0; mi < 4; ++mi)
#pragma unroll
                for (int ni = 0; ni < NI; ++ni)
                    acc[mi][ni] = __builtin_amdgcn_mfma_f32_16x16x32_bf16(af[mi], bf[ni], acc[mi][ni], 0, 0, 0);
        }
    }

#pragma unroll
    for (int mi = 0; mi < 4; ++mi)
#pragma unroll
        for (int ni = 0; ni < NI; ++ni)
#pragma unroll
            for (int r = 0; r < 4; ++r) {
                int row = m0 + wm + mi * 16 + quad * 4 + r;
                int col = n0 + wn + ni * 16 + l16;
                C[(size_t)row * N + col] = (TC)acc[mi][ni][r];
            }
}

// ---------------------------------------------------------------------------
// Merged RoPE (q,k) + sigma-permuted V-transpose.
// Blocks [0,8192): rope (q pre-scaled by kScale); [8192,9216): vtrans.
// vt position p within each 32-key group holds source key
//   sigma(p) = ((p&7)>>2)*16 + ((p>>3)&3)*4 + (p&3)
// so attn can feed exp'd S^T registers directly as the PV A-fragment.
// ---------------------------------------------------------------------------
__global__ __launch_bounds__(256) void rope_vtrans_kernel(const __bf16* __restrict__ qkv,
                                                          __bf16* __restrict__ qd,
                                                          __bf16* __restrict__ kd,
                                                          __bf16* __restrict__ vt) {
    __shared__ __bf16 tile[64 * 72] __attribute__((aligned(16)));

    if (blockIdx.x < 8192) {
        int tid = blockIdx.x * 256 + threadIdx.x;     // 2^21 threads
        int i = tid & 31;
        int h = (tid >> 5) & (kH - 1);
        int s = (tid >> 9) & (kS - 1);
        int b = tid >> 20;

        size_t rowbase = (size_t)(b * kS + s) * (3 * kE);
        int coff = h * kD + 2 * i;

        float qr = (float)qkv[rowbase + coff];
        float qi = (float)qkv[rowbase + coff + 1];
        float kr = (float)qkv[rowbase + kE + coff];
        float ki = (float)qkv[rowbase + kE + coff + 1];

        float inv = expf(-(float)i * (9.210340371976184f / 32.0f));  // 10000^(-i/32)
        float ang = (float)s * inv;
        float cv = cosf(ang);
        float sv = sinf(ang);

        size_t qbase = ((size_t)(b * kH + h) * kS + s) * kD + 2 * i;
        qd[qbase]     = (__bf16)(kScale * (qr * cv - qi * sv));
        qd[qbase + 1] = (__bf16)(kScale * (qr * sv + qi * cv));
        kd[qbase]     = (__bf16)(kr * cv - ki * sv);
        kd[qbase + 1] = (__bf16)(kr * sv + ki * cv);
    } else {
        int flat = blockIdx.x - 8192;                 // 0..1023
        int s0 = (flat & 31) * 64;
        int bh = flat >> 5;
        int b = bh >> 4, h = bh & 15;
        int tid = threadIdx.x;

#pragma unroll
        for (int p = 0; p < 2; ++p) {
            int c = tid + p * 256;           // 0..511
            int r = c >> 3, jc = c & 7;
            *(bf16x8*)&tile[r * 72 + jc * 8] =
                *(const bf16x8*)(qkv + (size_t)(b * kS + s0 + r) * (3 * kE) + 2 * kE + h * kD + jc * 8);
        }
        __syncthreads();
#pragma unroll
        for (int p = 0; p < 2; ++p) {
            int c = tid + p * 256;
            int d = c >> 3, jt = c & 7;      // output chunk jt: positions jt*8+u
            bf16x8 v;
#pragma unroll
            for (int u = 0; u < 8; ++u) {
                int src = (jt >> 2) * 32 + ((u >> 2) << 4) + ((jt & 3) << 2) + (u & 3);
                v[u] = tile[src * 72 + d];
            }
            *(bf16x8*)(vt + (size_t)(bh * kD + d) * kS + s0 + jt * 8) = v;
        }
    }
}

// ---------------------------------------------------------------------------
// Attention, flash-style, no-max softmax (|logit| <= ~6 pre-exp).
// BARRIER-FREE hot loop: K/V fragments are read directly from global
// (16B/lane contiguous, coalesced 16x64B per wave) and served by L1/L2 —
// no LDS staging, no __syncthreads, waves fully independent.
// Block = 4 waves: wave = qhalf*2 + khalf. Each wave: 32 q-rows (2 m-tiles)
// x 1024-key stripe. Partial (acc, lsum) add linearly (no-max softmax) ->
// one LDS combine + single barrier at the end.
// S^T = K*Q^T trick + sigma-permuted vt: exp'd registers feed PV directly.
// Row sums via ones-MFMA. Also converts w_out fp32->bf16 in the prologue.
// ---------------------------------------------------------------------------
__global__ __launch_bounds__(256, 4) void attn_kernel(const __bf16* __restrict__ qd,
                                                      const __bf16* __restrict__ kd,
                                                      const __bf16* __restrict__ vt,
                                                      __bf16* __restrict__ ctx,
                                                      const float* __restrict__ wout,
                                                      __bf16* __restrict__ woutb) {
    __shared__ float comb[2][64][40];   // [qhalf][lane][mi*20 + {0..3 sum, 4+nt*4+r acc}]

    const int lane  = threadIdx.x & 63;
    const int wave  = threadIdx.x >> 6;   // 0..3
    const int qhalf = wave >> 1;
    const int khalf = wave & 1;
    const int quad  = lane >> 4;
    const int l16   = lane & 15;

    // folded w_out convert: 1024 elems per block, 4 per thread (256 threads)
    {
        int base = blockIdx.x * 1024 + threadIdx.x * 4;
        float4 f = *(const float4*)(wout + base);
        bf16x4 r;
        r[0] = (__bf16)f.x; r[1] = (__bf16)f.y; r[2] = (__bf16)f.z; r[3] = (__bf16)f.w;
        *(bf16x4*)(woutb + base) = r;
    }

    // XCD-aware decode: flat%8 = XCD; each XCD owns heads 4x..4x+3
    const int flat = blockIdx.x;                  // 0..1023
    const int s    = flat >> 3;                   // 0..127
    const int bh   = (flat & 7) * 4 + (s >> 5);   // 0..31
    const int q0   = (s & 31) * 64;
    const int b  = bh >> 4;
    const int h  = bh & 15;

    const __bf16* qp = qd + (size_t)bh * kS * kD;
    const __bf16* kp = kd + (size_t)bh * kS * kD;
    const __bf16* vp = vt + (size_t)bh * kD * kS;

    // q fragments (pre-scaled): B-operand of S^T = K*Q^T
    bf16x8 aq[2][2];
#pragma unroll
    for (int mi = 0; mi < 2; ++mi) {
        const __bf16* qrow = qp + (size_t)(q0 + qhalf * 32 + mi * 16 + l16) * kD + quad * 8;
        aq[mi][0] = *(const bf16x8*)(qrow);
        aq[mi][1] = *(const bf16x8*)(qrow + 32);
    }

    bf16x8 vone;
#pragma unroll
    for (int u = 0; u < 8; ++u) vone[u] = (__bf16)1.0f;

    f32x4 zero = {0.f, 0.f, 0.f, 0.f};
    f32x4 acc[2][4];
    f32x4 asum[2];
#pragma unroll
    for (int mi = 0; mi < 2; ++mi) {
        asum[mi] = zero;
#pragma unroll
        for (int i = 0; i < 4; ++i) acc[mi][i] = zero;
    }

    // per-lane base pointers for K and V fragment streams
    const __bf16* kfrag = kp + (size_t)(khalf * 1024 + l16) * kD + quad * 8;      // +t2*16*kD, +h*32
    const __bf16* vfrag = vp + (size_t)l16 * kS + khalf * 1024 + quad * 8;        // +nt*16*kS, +ks*32

#pragma unroll 2
    for (int it = 0; it < 16; ++it) {
        const __bf16* kt = kfrag + it * (64 * kD);
        const __bf16* vtile = vfrag + it * 64;
#pragma unroll
        for (int ks = 0; ks < 2; ++ks) {     // 32-key halves of the 64-key tile
            // K fragments as A-operand: A[m=key=l16][k=d=quad*8+j]
            const __bf16* kk = kt + ks * (32 * kD);
            bf16x8 ak00 = *(const bf16x8*)(kk);
            bf16x8 ak01 = *(const bf16x8*)(kk + 32);
            bf16x8 ak10 = *(const bf16x8*)(kk + 16 * kD);
            bf16x8 ak11 = *(const bf16x8*)(kk + 16 * kD + 32);
            bf16x8 ap[2];
#pragma unroll
            for (int mi = 0; mi < 2; ++mi) {
                f32x4 s0 = __builtin_amdgcn_mfma_f32_16x16x32_bf16(ak00, aq[mi][0], zero, 0, 0, 0);
                s0 = __builtin_amdgcn_mfma_f32_16x16x32_bf16(ak01, aq[mi][1], s0, 0, 0, 0);
                f32x4 s1 = __builtin_amdgcn_mfma_f32_16x16x32_bf16(ak10, aq[mi][0], zero, 0, 0, 0);
                s1 = __builtin_amdgcn_mfma_f32_16x16x32_bf16(ak11, aq[mi][1], s1, 0, 0, 0);
                bf16x8 p;
                p[0] = (__bf16)__expf(s0[0]); p[1] = (__bf16)__expf(s0[1]);
                p[2] = (__bf16)__expf(s0[2]); p[3] = (__bf16)__expf(s0[3]);
                p[4] = (__bf16)__expf(s1[0]); p[5] = (__bf16)__expf(s1[1]);
                p[6] = (__bf16)__expf(s1[2]); p[7] = (__bf16)__expf(s1[3]);
                ap[mi] = p;
            }
#pragma unroll
            for (int mi = 0; mi < 2; ++mi)
                asum[mi] = __builtin_amdgcn_mfma_f32_16x16x32_bf16(ap[mi], vone, asum[mi], 0, 0, 0);
            // PV: V frags (sigma-permuted order) shared across both m-tiles
#pragma unroll
            for (int nt = 0; nt < 4; ++nt) {
                bf16x8 bv = *(const bf16x8*)(vtile + (size_t)(nt * 16) * kS + ks * 32);
                acc[0][nt] = __builtin_amdgcn_mfma_f32_16x16x32_bf16(ap[0], bv, acc[0][nt], 0, 0, 0);
                acc[1][nt] = __builtin_amdgcn_mfma_f32_16x16x32_bf16(ap[1], bv, acc[1][nt], 0, 0, 0);
            }
        }
    }

    // combine key-halves: khalf=1 waves publish partials, khalf=0 waves reduce
    if (khalf) {
#pragma unroll
        for (int mi = 0; mi < 2; ++mi) {
            *(f32x4*)&comb[qhalf][lane][mi * 20] = asum[mi];
#pragma unroll
            for (int nt = 0; nt < 4; ++nt)
                *(f32x4*)&comb[qhalf][lane][mi * 20 + 4 + nt * 4] = acc[mi][nt];
        }
    }
    __syncthreads();
    if (!khalf) {
#pragma unroll
        for (int mi = 0; mi < 2; ++mi)
#pragma unroll
            for (int r = 0; r < 4; ++r) {
                float l = asum[mi][r] + comb[qhalf][lane][mi * 20 + r];
                float inv_l = 1.0f / l;
                int srow_q = q0 + qhalf * 32 + mi * 16 + quad * 4 + r;
#pragma unroll
                for (int nt = 0; nt < 4; ++nt) {
                    float o = acc[mi][nt][r] + comb[qhalf][lane][mi * 20 + 4 + nt * 4 + r];
                    int col = h * kD + nt * 16 + l16;
                    ctx[(size_t)(b * kS + srow_q) * kE + col] = (__bf16)(o * inv_l);
                }
            }
    }
}

// ---------------------------------------------------------------------------
extern "C" void kernel_launch(void* const* d_in, const int* in_sizes, int n_in,
                              void* d_out, int out_size, void* d_ws, size_t ws_size,
                              hipStream_t stream) {
    const float* query = (const float*)d_in[0];
    // d_in[1] (key) and d_in[2] (value) are unused by the reference
    const float* w_qkv = (const float*)d_in[3];
    const float* w_out = (const float*)d_in[4];
    float* out = (float*)d_out;

    const int M = kBATCH * kS;             // 4096
    const int nQ = M * kE;                 // 4,194,304
    const int nWqkv = 3 * kE * kE;         // 3,145,728

    // workspace (48 MB, lifetime-overlapped):
    //   [0,24M)   qkv_raw (gemm1 out) -> later ctx [0,8M) + w_out_b [8M,10M)
    //   [24,48M)  qd | kd | vt ; query_b/w_qkv_b alias qd/kd pre-rope
    char* ws = (char*)d_ws;
    __bf16* qkv_raw = (__bf16*)ws;
    __bf16* ctx     = (__bf16*)ws;                       // alias, post-vtrans
    __bf16* w_out_b = (__bf16*)(ws + (size_t)8388608);   // alias, post-vtrans
    __bf16* qd      = (__bf16*)(ws + (size_t)25165824);
    __bf16* kd      = (__bf16*)(ws + (size_t)33554432);
    __bf16* vt      = (__bf16*)(ws + (size_t)41943040);
    __bf16* query_b = qd;      // alias, dead after GEMM1
    __bf16* w_qkv_b = kd;      // alias, dead after GEMM1

    // 1) fp32 -> bf16 for query + w_qkv
    cvt2_kernel<<<(nQ + nWqkv) / 1024, 256, 0, stream>>>(query, query_b, nQ, w_qkv, w_qkv_b);

    // 2) QKV projection (128x128 tile, BK=64)
    gemm_bt_kernel<128, __bf16>
        <<<dim3(3 * kE / 128, M / 128), 256, 0, stream>>>(query_b, w_qkv_b, qkv_raw, M, 3 * kE, kE);

    // 3) RoPE on q,k (q pre-scaled) + sigma-permuted V transpose
    rope_vtrans_kernel<<<8192 + 1024, 256, 0, stream>>>(qkv_raw, qd, kd, vt);

    // 4) attention (barrier-free, key-split; + folded w_out convert)
    attn_kernel<<<1024, 256, 0, stream>>>(qd, kd, vt, ctx, w_out, w_out_b);

    // 5) output projection (128x64 tile -> 512 blocks, fp32 out)
    gemm_bt_kernel<64, float>
        <<<dim3(kE / 64, M / 128), 256, 0, stream>>>(ctx, w_out_b, out, M, kE, kE);
}

// Round 8
// 207.356 us; speedup vs baseline: 1.3432x; 1.3432x over previous
//
#include <hip/hip_runtime.h>
#include <math.h>

typedef __attribute__((ext_vector_type(8))) __bf16 bf16x8;
typedef __attribute__((ext_vector_type(4))) __bf16 bf16x4;
typedef __attribute__((ext_vector_type(4))) float f32x4;

constexpr int kBATCH = 2;
constexpr int kS = 2048;
constexpr int kE = 1024;
constexpr int kH = 16;
constexpr int kD = 64;
constexpr float kScale = 0.125f;   // D^-0.5, pre-applied to Q in rope

// async global->LDS, 16B per lane. LDS dest is wave-uniform base + lane*16.
__device__ inline void gl2lds16(const void* g, void* l) {
    __builtin_amdgcn_global_load_lds((const __attribute__((address_space(1))) void*)g,
                                     (__attribute__((address_space(3))) void*)l, 16, 0, 0);
}

// ---------------------------------------------------------------------------
// fp32 -> bf16 convert, two buffers in one launch (range select).
// ---------------------------------------------------------------------------
__global__ __launch_bounds__(256) void cvt2_kernel(const float* __restrict__ a, __bf16* __restrict__ oa, int na,
                                                   const float* __restrict__ b, __bf16* __restrict__ ob) {
    int idx = (blockIdx.x * 256 + threadIdx.x) * 4;
    const float* src;
    __bf16* dst;
    if (idx < na) { src = a + idx; dst = oa + idx; }
    else          { src = b + (idx - na); dst = ob + (idx - na); }
    float4 f = *(const float4*)src;
    bf16x4 r;
    r[0] = (__bf16)f.x; r[1] = (__bf16)f.y; r[2] = (__bf16)f.z; r[3] = (__bf16)f.w;
    *(bf16x4*)dst = r;
}

// ---------------------------------------------------------------------------
// GEMM: C[m,n] = sum_k A[m,k] * W[n,k], bf16 in. Tile 128 x TN, BK=64,
// global_load_lds staging with XOR-chunk swizzle (conflict-free frag reads).
// ---------------------------------------------------------------------------
template <int TN, typename TC>
__global__ __launch_bounds__(256) void gemm_bt_kernel(const __bf16* __restrict__ A,
                                                      const __bf16* __restrict__ W,
                                                      TC* __restrict__ C,
                                                      int M, int N, int K) {
    constexpr int NI = TN / 32;        // n-frags per wave
    __shared__ __bf16 As[128 * 64] __attribute__((aligned(16)));
    __shared__ __bf16 Bs[TN * 64] __attribute__((aligned(16)));

    const int tid  = threadIdx.x;
    const int lane = tid & 63;
    const int quad = lane >> 4;
    const int l16  = lane & 15;
    const int rx   = l16 & 7;
    const int wave = tid >> 6;
    const int wm   = (wave >> 1) * 64;
    const int wn   = (wave & 1) * (TN / 2);
    const int m0   = blockIdx.y * 128;
    const int n0   = blockIdx.x * TN;

    const int srow8  = lane >> 3;                  // 0..7
    const int schunk = ((lane & 7) ^ srow8) * 8;   // swizzled source col (elems)

    f32x4 zero = {0.f, 0.f, 0.f, 0.f};
    f32x4 acc[4][NI];
#pragma unroll
    for (int i = 0; i < 4; ++i)
#pragma unroll
        for (int j = 0; j < NI; ++j) acc[i][j] = zero;

    for (int kt = 0; kt < K; kt += 64) {
        __syncthreads();   // previous tile's readers done
#pragma unroll
        for (int i = 0; i < 4; ++i) {
            int rbase = wave * 32 + i * 8;
            gl2lds16(A + (size_t)(m0 + rbase + srow8) * K + kt + schunk, &As[rbase * 64]);
        }
#pragma unroll
        for (int i = 0; i < NI; ++i) {
            int rbase = wave * (TN / 4) + i * 8;
            gl2lds16(W + (size_t)(n0 + rbase + srow8) * K + kt + schunk, &Bs[rbase * 64]);
        }
        __syncthreads();   // loads landed

#pragma unroll
        for (int kk = 0; kk < 2; ++kk) {
            bf16x8 af[4], bf[NI];
#pragma unroll
            for (int mi = 0; mi < 4; ++mi)
                af[mi] = *(const bf16x8*)(&As[(wm + mi * 16 + l16) * 64 + (((kk * 4 + quad) ^ rx)) * 8]);
#pragma unroll
            for (int ni = 0; ni < NI; ++ni)
                bf[ni] = *(const bf16x8*)(&Bs[(wn + ni * 16 + l16) * 64 + (((kk * 4 + quad) ^ rx)) * 8]);
#pragma unroll
            for (int mi = 0; mi < 4; ++mi)
#pragma unroll
                for (int ni = 0; ni < NI; ++ni)
                    acc[mi][ni] = __builtin_amdgcn_mfma_f32_16x16x32_bf16(af[mi], bf[ni], acc[mi][ni], 0, 0, 0);
        }
    }

#pragma unroll
    for (int mi = 0; mi < 4; ++mi)
#pragma unroll
        for (int ni = 0; ni < NI; ++ni)
#pragma unroll
            for (int r = 0; r < 4; ++r) {
                int row = m0 + wm + mi * 16 + quad * 4 + r;
                int col = n0 + wn + ni * 16 + l16;
                C[(size_t)row * N + col] = (TC)acc[mi][ni][r];
            }
}

// ---------------------------------------------------------------------------
// Merged RoPE (q,k) + sigma-permuted V-transpose.
// Blocks [0,8192): rope (q pre-scaled by kScale); [8192,9216): vtrans.
// vt position p within each 32-key group holds source key
//   sigma(p) = ((p&7)>>2)*16 + ((p>>3)&3)*4 + (p&3)
// so attn can feed exp'd S^T registers directly as the PV A-fragment.
// ---------------------------------------------------------------------------
__global__ __launch_bounds__(256) void rope_vtrans_kernel(const __bf16* __restrict__ qkv,
                                                          __bf16* __restrict__ qd,
                                                          __bf16* __restrict__ kd,
                                                          __bf16* __restrict__ vt) {
    __shared__ __bf16 tile[64 * 72] __attribute__((aligned(16)));

    if (blockIdx.x < 8192) {
        int tid = blockIdx.x * 256 + threadIdx.x;     // 2^21 threads
        int i = tid & 31;
        int h = (tid >> 5) & (kH - 1);
        int s = (tid >> 9) & (kS - 1);
        int b = tid >> 20;

        size_t rowbase = (size_t)(b * kS + s) * (3 * kE);
        int coff = h * kD + 2 * i;

        float qr = (float)qkv[rowbase + coff];
        float qi = (float)qkv[rowbase + coff + 1];
        float kr = (float)qkv[rowbase + kE + coff];
        float ki = (float)qkv[rowbase + kE + coff + 1];

        float inv = expf(-(float)i * (9.210340371976184f / 32.0f));  // 10000^(-i/32)
        float ang = (float)s * inv;
        float cv = cosf(ang);
        float sv = sinf(ang);

        size_t qbase = ((size_t)(b * kH + h) * kS + s) * kD + 2 * i;
        qd[qbase]     = (__bf16)(kScale * (qr * cv - qi * sv));
        qd[qbase + 1] = (__bf16)(kScale * (qr * sv + qi * cv));
        kd[qbase]     = (__bf16)(kr * cv - ki * sv);
        kd[qbase + 1] = (__bf16)(kr * sv + ki * cv);
    } else {
        int flat = blockIdx.x - 8192;                 // 0..1023
        int s0 = (flat & 31) * 64;
        int bh = flat >> 5;
        int b = bh >> 4, h = bh & 15;
        int tid = threadIdx.x;

#pragma unroll
        for (int p = 0; p < 2; ++p) {
            int c = tid + p * 256;           // 0..511
            int r = c >> 3, jc = c & 7;
            *(bf16x8*)&tile[r * 72 + jc * 8] =
                *(const bf16x8*)(qkv + (size_t)(b * kS + s0 + r) * (3 * kE) + 2 * kE + h * kD + jc * 8);
        }
        __syncthreads();
#pragma unroll
        for (int p = 0; p < 2; ++p) {
            int c = tid + p * 256;
            int d = c >> 3, jt = c & 7;      // output chunk jt: positions jt*8+u
            bf16x8 v;
#pragma unroll
            for (int u = 0; u < 8; ++u) {
                int src = (jt >> 2) * 32 + ((u >> 2) << 4) + ((jt & 3) << 2) + (u & 3);
                v[u] = tile[src * 72 + d];
            }
            *(bf16x8*)(vt + (size_t)(bh * kD + d) * kS + s0 + jt * 8) = v;
        }
    }
}

// ---------------------------------------------------------------------------
// Attention, flash-style, no-max softmax (|logit| <= ~6 pre-exp).
// r5 structure (64-key LDS dbuf via global_load_lds, S^T=K*Q^T + sigma-vt,
// ones-MFMA row sums) but 4 waves x 16 q-rows instead of 2 x 32:
// per-wave chain halves, waves/CU doubles (16), staging split over 4 waves.
// ---------------------------------------------------------------------------
__global__ __launch_bounds__(256, 4) void attn_kernel(const __bf16* __restrict__ qd,
                                                      const __bf16* __restrict__ kd,
                                                      const __bf16* __restrict__ vt,
                                                      __bf16* __restrict__ ctx,
                                                      const float* __restrict__ wout,
                                                      __bf16* __restrict__ woutb) {
    __shared__ __bf16 Ks[2][64 * 64] __attribute__((aligned(16)));
    __shared__ __bf16 Vs[2][64 * 64] __attribute__((aligned(16)));

    const int lane = threadIdx.x & 63;
    const int wave = threadIdx.x >> 6;   // 0..3
    const int quad = lane >> 4;
    const int l16  = lane & 15;
    const int rx   = l16 & 7;

    // folded w_out convert: 1024 elems per block, 4 per thread (exact tiling)
    {
        int base = blockIdx.x * 1024 + threadIdx.x * 4;
        float4 f = *(const float4*)(wout + base);
        bf16x4 r;
        r[0] = (__bf16)f.x; r[1] = (__bf16)f.y; r[2] = (__bf16)f.z; r[3] = (__bf16)f.w;
        *(bf16x4*)(woutb + base) = r;
    }

    // XCD-aware decode: flat%8 = XCD; each XCD owns heads 4x..4x+3
    const int flat = blockIdx.x;                  // 0..1023
    const int s    = flat >> 3;                   // 0..127
    const int bh   = (flat & 7) * 4 + (s >> 5);   // 0..31
    const int q0   = (s & 31) * 64;
    const int b  = bh >> 4;
    const int h  = bh & 15;

    const __bf16* qp = qd + (size_t)bh * kS * kD;
    const __bf16* kp = kd + (size_t)bh * kS * kD;
    const __bf16* vp = vt + (size_t)bh * kD * kS;

    const int srow8  = lane >> 3;
    const int schunk = ((lane & 7) ^ srow8) * 8;

    // q fragments (pre-scaled): B-operand of S^T = K*Q^T. 16 q-rows per wave.
    bf16x8 aq0, aq1;
    {
        const __bf16* qrow = qp + (size_t)(q0 + wave * 16 + l16) * kD + quad * 8;
        aq0 = *(const bf16x8*)(qrow);
        aq1 = *(const bf16x8*)(qrow + 32);
    }

    bf16x8 vone;
#pragma unroll
    for (int u = 0; u < 8; ++u) vone[u] = (__bf16)1.0f;

    f32x4 zero = {0.f, 0.f, 0.f, 0.f};
    f32x4 acc[4];
    f32x4 asum = zero;
#pragma unroll
    for (int i = 0; i < 4; ++i) acc[i] = zero;

    // prologue: stage tile 0 into buf 0 (2 K + 2 V instrs per wave, 4 waves)
#pragma unroll
    for (int c = 0; c < 2; ++c) {
        int i = wave * 2 + c;
        gl2lds16(kp + (size_t)(i * 8 + srow8) * kD + schunk, &Ks[0][i * 512]);
        gl2lds16(vp + (size_t)(i * 8 + srow8) * kS + schunk, &Vs[0][i * 512]);
    }

    const int nT = kS / 64;
    for (int it = 0; it < nT; ++it) {
        const int buf = it & 1;
        __syncthreads();   // tile `it` resident; buf^1 compute done
        if (it + 1 < nT) {
            int t1 = (it + 1) * 64;
#pragma unroll
            for (int c = 0; c < 2; ++c) {
                int i = wave * 2 + c;
                gl2lds16(kp + (size_t)(t1 + i * 8 + srow8) * kD + schunk, &Ks[buf ^ 1][i * 512]);
                gl2lds16(vp + (size_t)(i * 8 + srow8) * kS + t1 + schunk, &Vs[buf ^ 1][i * 512]);
            }
        }

        // QK^T: 4 key-16-groups x 2 k-steps = 8 MFMA
        f32x4 sg[4];
#pragma unroll
        for (int g = 0; g < 4; ++g) {
            int krow = g * 16 + l16;
            bf16x8 a0 = *(const bf16x8*)&Ks[buf][krow * 64 + ((quad      ^ rx)) * 8];
            bf16x8 a1 = *(const bf16x8*)&Ks[buf][krow * 64 + (((quad + 4) ^ rx)) * 8];
            f32x4 t = __builtin_amdgcn_mfma_f32_16x16x32_bf16(a0, aq0, zero, 0, 0, 0);
            sg[g] = __builtin_amdgcn_mfma_f32_16x16x32_bf16(a1, aq1, t, 0, 0, 0);
        }

        // exp -> two PV A-fragments (keys 0..31, 32..63; sigma-matched to vt)
        bf16x8 ap0, ap1;
#pragma unroll
        for (int r = 0; r < 4; ++r) {
            ap0[r]     = (__bf16)__expf(sg[0][r]);
            ap0[4 + r] = (__bf16)__expf(sg[1][r]);
            ap1[r]     = (__bf16)__expf(sg[2][r]);
            ap1[4 + r] = (__bf16)__expf(sg[3][r]);
        }

        asum = __builtin_amdgcn_mfma_f32_16x16x32_bf16(ap0, vone, asum, 0, 0, 0);
        asum = __builtin_amdgcn_mfma_f32_16x16x32_bf16(ap1, vone, asum, 0, 0, 0);

        // PV: 2 ks x 4 nt = 8 MFMA
#pragma unroll
        for (int nt = 0; nt < 4; ++nt) {
            int drow = nt * 16 + l16;
            bf16x8 bv0 = *(const bf16x8*)&Vs[buf][drow * 64 + ((quad      ^ (drow & 7))) * 8];
            bf16x8 bv1 = *(const bf16x8*)&Vs[buf][drow * 64 + (((quad + 4) ^ (drow & 7))) * 8];
            acc[nt] = __builtin_amdgcn_mfma_f32_16x16x32_bf16(ap0, bv0, acc[nt], 0, 0, 0);
            acc[nt] = __builtin_amdgcn_mfma_f32_16x16x32_bf16(ap1, bv1, acc[nt], 0, 0, 0);
        }
    }

#pragma unroll
    for (int r = 0; r < 4; ++r) {
        float inv_l = 1.0f / asum[r];
        int srow_q = q0 + wave * 16 + quad * 4 + r;
#pragma unroll
        for (int nt = 0; nt < 4; ++nt) {
            int col = h * kD + nt * 16 + l16;
            ctx[(size_t)(b * kS + srow_q) * kE + col] = (__bf16)(acc[nt][r] * inv_l);
        }
    }
}

// ---------------------------------------------------------------------------
extern "C" void kernel_launch(void* const* d_in, const int* in_sizes, int n_in,
                              void* d_out, int out_size, void* d_ws, size_t ws_size,
                              hipStream_t stream) {
    const float* query = (const float*)d_in[0];
    // d_in[1] (key) and d_in[2] (value) are unused by the reference
    const float* w_qkv = (const float*)d_in[3];
    const float* w_out = (const float*)d_in[4];
    float* out = (float*)d_out;

    const int M = kBATCH * kS;             // 4096
    const int nQ = M * kE;                 // 4,194,304
    const int nWqkv = 3 * kE * kE;         // 3,145,728

    // workspace (48 MB, lifetime-overlapped):
    //   [0,24M)   qkv_raw (gemm1 out) -> later ctx [0,8M) + w_out_b [8M,10M)
    //   [24,48M)  qd | kd | vt ; query_b/w_qkv_b alias qd/kd pre-rope
    char* ws = (char*)d_ws;
    __bf16* qkv_raw = (__bf16*)ws;
    __bf16* ctx     = (__bf16*)ws;                       // alias, post-vtrans
    __bf16* w_out_b = (__bf16*)(ws + (size_t)8388608);   // alias, post-vtrans
    __bf16* qd      = (__bf16*)(ws + (size_t)25165824);
    __bf16* kd      = (__bf16*)(ws + (size_t)33554432);
    __bf16* vt      = (__bf16*)(ws + (size_t)41943040);
    __bf16* query_b = qd;      // alias, dead after GEMM1
    __bf16* w_qkv_b = kd;      // alias, dead after GEMM1

    // 1) fp32 -> bf16 for query + w_qkv
    cvt2_kernel<<<(nQ + nWqkv) / 1024, 256, 0, stream>>>(query, query_b, nQ, w_qkv, w_qkv_b);

    // 2) QKV projection (128x128 tile, BK=64)
    gemm_bt_kernel<128, __bf16>
        <<<dim3(3 * kE / 128, M / 128), 256, 0, stream>>>(query_b, w_qkv_b, qkv_raw, M, 3 * kE, kE);

    // 3) RoPE on q,k (q pre-scaled) + sigma-permuted V transpose
    rope_vtrans_kernel<<<8192 + 1024, 256, 0, stream>>>(qkv_raw, qd, kd, vt);

    // 4) attention (4 waves x 16 q-rows, LDS dbuf; + folded w_out convert)
    attn_kernel<<<1024, 256, 0, stream>>>(qd, kd, vt, ctx, w_out, w_out_b);

    // 5) output projection (128x64 tile -> 512 blocks, fp32 out)
    gemm_bt_kernel<64, float>
        <<<dim3(kE / 64, M / 128), 256, 0, stream>>>(ctx, w_out_b, out, M, kE, kE);
}